// Round 17
// baseline (68.397 us; speedup 1.0000x reference)
//
#include <hip/hip_runtime.h>
#include <hip/hip_bf16.h>

#define BB 8192
#define TT 50
#define II 50
#define HH 10
#define CC 5

__device__ __forceinline__ float fast_tanh(float x) {
    float e = __expf(2.0f * x);
    return 1.0f - 2.0f * __builtin_amdgcn_rcpf(e + 1.0f);
}
__device__ __forceinline__ unsigned short bfbits(float f) {
    __hip_bfloat16 h = __float2bfloat16(f);
    union { __hip_bfloat16 h; unsigned short u; } cv;
    cv.h = h;
    return cv.u;
}
__device__ __forceinline__ unsigned packbf(float a, float b) {   // low = a, high = b
    return ((unsigned)bfbits(b) << 16) | (unsigned)bfbits(a);
}
// partner value from lane j^1 (DPP quad_perm(1,0,3,2) — VALU, not DS)
__device__ __forceinline__ float qswap1(float x) {
    return __uint_as_float((unsigned)__builtin_amdgcn_update_dpp(
        (int)__float_as_uint(x), (int)__float_as_uint(x), 0xB1, 0xF, 0xF, true));
}
// unpack dword of 2 bf16 -> 2 floats (2 VALU)
#define UNPK(d, e, o) { unsigned _d = (d); e = __uint_as_float(_d << 16); o = __uint_as_float(_d & 0xFFFF0000u); }

// K1: P[t][j][b] = sum_i x[b][t][i] * Wih0[j][i] + (bih0[j]+bhh0[j])
// (R10's exact version — ~15.5 us, coalesced dword stores)
__global__ __launch_bounds__(256) void k_proj0(
    const float* __restrict__ x, const float* __restrict__ Wih0,
    const float* __restrict__ bih0, const float* __restrict__ bhh0,
    float* __restrict__ P) {
    int gid = blockIdx.x * 256 + threadIdx.x;
    int b = gid & (BB - 1);
    int t = gid >> 13;
    const float2* xr = (const float2*)(x + ((size_t)b * TT + t) * II);
    float2 xv[II / 2];
#pragma unroll
    for (int i = 0; i < II / 2; i++) xv[i] = xr[i];
#pragma unroll
    for (int j = 0; j < HH; j++) {
        float a = bih0[j] + bhh0[j];
        const float2* w = (const float2*)(Wih0 + j * II);
#pragma unroll
        for (int i = 0; i < II / 2; i++) {
            float2 wv = w[i];
            a = fmaf(wv.x, xv[i].x, a);
            a = fmaf(wv.y, xv[i].y, a);
        }
        P[((size_t)t * HH + j) * BB + b] = a;
    }
}

// K2: fused 3-layer recurrence + FC. R10/R16 structure with bf16-PACKED h state:
// 5 ds_read_b128 + 1 ds_write_b128 + 2 FC reads = 8 DS/iter (was 13).
// 16 lanes/batch, 4 batches/wave, 2048 waves = 8 waves/CU. Parity double-buffer,
// in-order DS within wave, no in-loop barriers. ILP3 stagger (L0@i, L1@i-1, L2@i-2).
__global__ __launch_bounds__(256, 2) void k_fused(
    const float* __restrict__ h0all,
    const float* __restrict__ Whh0,
    const float* __restrict__ Wih1, const float* __restrict__ Whh1,
    const float* __restrict__ bih1, const float* __restrict__ bhh1,
    const float* __restrict__ Wih2, const float* __restrict__ Whh2,
    const float* __restrict__ bih2, const float* __restrict__ bhh2,
    const float* __restrict__ fcw, const float* __restrict__ fcb,
    const float* __restrict__ P, float* __restrict__ out) {
    __shared__ __align__(16) float sfc8[(TT * HH + 8) * 8];   // [t*10+j][8], 16.3 KB
    __shared__ __align__(16) unsigned shp[2][16][5][4];       // [par][g16][pair][{h0,h1,h2,pad}]

    const int tid = threadIdx.x;
    const int j = tid & 15;
    const int g16 = tid >> 4;
    const int b = blockIdx.x * 16 + g16;
    const bool jv = (j < HH);
    const bool wr = jv && !(j & 1);   // even lanes 0,2,4,6,8 write pairs

    // stage padded transposed FC weights: sfc8[(t*HH+j)*8 + c] = fcw[c][t*HH+j]
    for (int idx = tid; idx < (TT * HH + 8) * 8; idx += 256) {
        int r = idx >> 3, c = idx & 7;
        sfc8[idx] = (r < TT * HH && c < CC) ? fcw[(size_t)c * (TT * HH) + r] : 0.0f;
    }

    // per-lane weight rows (row j); zeros for j >= 10
    float w0[HH], wi1[HH], wh1[HH], wi2[HH], wh2[HH];
    float bs1 = 0.0f, bs2 = 0.0f, h0i = 0.0f, h1i = 0.0f, h2i = 0.0f;
    if (jv) {
#pragma unroll
        for (int k = 0; k < HH; k++) {
            w0[k]  = Whh0[j * HH + k];
            wi1[k] = Wih1[j * HH + k];
            wh1[k] = Whh1[j * HH + k];
            wi2[k] = Wih2[j * HH + k];
            wh2[k] = Whh2[j * HH + k];
        }
        bs1 = bih1[j] + bhh1[j];
        bs2 = bih2[j] + bhh2[j];
        h0i = h0all[(size_t)b * HH + j];
        h1i = h0all[(size_t)BB * HH + (size_t)b * HH + j];
        h2i = h0all[(size_t)2 * BB * HH + (size_t)b * HH + j];
    } else {
#pragma unroll
        for (int k = 0; k < HH; k++) {
            w0[k] = wi1[k] = wh1[k] = wi2[k] = wh2[k] = 0.0f;
        }
    }

    // prologue: packed initial state into parity-1 (read by iteration 0)
    {
        float p0 = qswap1(h0i), p1 = qswap1(h1i), p2 = qswap1(h2i);
        if (wr) {
            uint4 wv;
            wv.x = packbf(h0i, p0);
            wv.y = packbf(h1i, p1);
            wv.z = packbf(h2i, p2);
            wv.w = 0u;
            *(uint4*)&shp[1][g16][j >> 1][0] = wv;
        }
    }

    __syncthreads();   // sfc8 ready; waves independent afterwards

    float acc[CC] = {0.0f, 0.0f, 0.0f, 0.0f, 0.0f};

    // P base pointer; [t][j][b] layout. 3-deep rotation.
    const float* Pb = P + (size_t)j * BB + b;
    float pc = jv ? Pb[(size_t)0 * HH * BB] : 0.0f;
    float p1 = jv ? Pb[(size_t)1 * HH * BB] : 0.0f;
    float p2 = jv ? Pb[(size_t)2 * HH * BB] : 0.0f;

    const unsigned* shR = &shp[1][g16][0][0];
    unsigned*       shW = &shp[0][g16][0][0];

#pragma unroll 1
    for (int i = 0; i < TT + 2; i++) {
        // ---- 5 packed reads (prev iteration's writes; in-order DS) ----
        uint4 q0 = *(const uint4*)(shR + 0);
        uint4 q1 = *(const uint4*)(shR + 4);
        uint4 q2 = *(const uint4*)(shR + 8);
        uint4 q3 = *(const uint4*)(shR + 12);
        uint4 q4 = *(const uint4*)(shR + 16);

        // ---- prefetch P for t = i+3 (clamped) ----
        int tp = (i + 3 < TT) ? (i + 3) : (TT - 1);
        float p3 = jv ? Pb[(size_t)tp * HH * BB] : 0.0f;

        // ---- FC weights for t = i-2 (clamped; padded-safe) ----
        int tauc = (i >= 2) ? (i - 2) : 0;
        const float* fb = &sfc8[(tauc * HH + j) * 8];
        float4 f4 = *(const float4*)fb;
        float  f1 = fb[4];

        // ---- unpack 30 h values ----
        float H0[HH], H1[HH], H2[HH];
        UNPK(q0.x, H0[0], H0[1]) UNPK(q0.y, H1[0], H1[1]) UNPK(q0.z, H2[0], H2[1])
        UNPK(q1.x, H0[2], H0[3]) UNPK(q1.y, H1[2], H1[3]) UNPK(q1.z, H2[2], H2[3])
        UNPK(q2.x, H0[4], H0[5]) UNPK(q2.y, H1[4], H1[5]) UNPK(q2.z, H2[4], H2[5])
        UNPK(q3.x, H0[6], H0[7]) UNPK(q3.y, H1[6], H1[7]) UNPK(q3.z, H2[6], H2[7])
        UNPK(q4.x, H0[8], H0[9]) UNPK(q4.y, H1[8], H1[9]) UNPK(q4.z, H2[8], H2[9])

        // ---- three staggered layer rows ----
        float a0 = pc, a1 = bs1, a2 = bs2;
#pragma unroll
        for (int k = 0; k < HH; k++) {
            a0 = fmaf(w0[k],  H0[k], a0);
            a1 = fmaf(wi1[k], H0[k], a1);
            a1 = fmaf(wh1[k], H1[k], a1);
            a2 = fmaf(wi2[k], H1[k], a2);
            a2 = fmaf(wh2[k], H2[k], a2);
        }
        float t0 = fast_tanh(a0);
        float t1 = fast_tanh(a1);
        float t2 = fast_tanh(a2);

        // ---- FC accumulate for t = i-2 (i uniform -> cheap SALU branch) ----
        if (i >= 2 && jv) {
            float rl = fmaxf(t2, 0.0f);
            acc[0] = fmaf(f4.x, rl, acc[0]);
            acc[1] = fmaf(f4.y, rl, acc[1]);
            acc[2] = fmaf(f4.z, rl, acc[2]);
            acc[3] = fmaf(f4.w, rl, acc[3]);
            acc[4] = fmaf(f1,  rl, acc[4]);
        }

        // ---- pack + single write (init overrides during pipeline fill) ----
        float v0 = t0;
        float v1 = (i == 0) ? h1i : t1;
        float v2 = (i <= 1) ? h2i : t2;
        float o0 = qswap1(v0), o1 = qswap1(v1), o2 = qswap1(v2);
        if (wr) {
            uint4 wv;
            wv.x = packbf(v0, o0);
            wv.y = packbf(v1, o1);
            wv.z = packbf(v2, o2);
            wv.w = 0u;
            *(uint4*)(shW + (j >> 1) * 4) = wv;
        }
        // parity pointer swap + P rotation
        unsigned* tmp = (unsigned*)shR; shR = shW; shW = tmp;
        pc = p1; p1 = p2; p2 = p3;
    }

    // reduce acc across the 16-lane group (lanes j>=10 hold zeros)
#pragma unroll
    for (int c = 0; c < CC; c++) {
        float a = acc[c];
        a += __shfl_xor(a, 1);
        a += __shfl_xor(a, 2);
        a += __shfl_xor(a, 4);
        a += __shfl_xor(a, 8);
        acc[c] = a + fcb[c];
    }
    if (j == 0) {
#pragma unroll
        for (int c = 0; c < CC; c++) out[(size_t)b * CC + c] = acc[c];
    }
}

extern "C" void kernel_launch(void* const* d_in, const int* in_sizes, int n_in,
                              void* d_out, int out_size, void* d_ws, size_t ws_size,
                              hipStream_t stream) {
    const float* x    = (const float*)d_in[0];
    const float* h0   = (const float*)d_in[1];
    const float* Wih0 = (const float*)d_in[2];
    const float* Whh0 = (const float*)d_in[3];
    const float* bih0 = (const float*)d_in[4];
    const float* bhh0 = (const float*)d_in[5];
    const float* Wih1 = (const float*)d_in[6];
    const float* Whh1 = (const float*)d_in[7];
    const float* bih1 = (const float*)d_in[8];
    const float* bhh1 = (const float*)d_in[9];
    const float* Wih2 = (const float*)d_in[10];
    const float* Whh2 = (const float*)d_in[11];
    const float* bih2 = (const float*)d_in[12];
    const float* bhh2 = (const float*)d_in[13];
    const float* fcw  = (const float*)d_in[14];
    const float* fcb  = (const float*)d_in[15];
    float* out = (float*)d_out;
    float* P   = (float*)d_ws;   // [T][H][B] = 16.38 MB

    k_proj0<<<(BB * TT) / 256, 256, 0, stream>>>(x, Wih0, bih0, bhh0, P);
    k_fused<<<BB / 16, 256, 0, stream>>>(h0, Whh0, Wih1, Whh1, bih1, bhh1,
                                         Wih2, Whh2, bih2, bhh2, fcw, fcb, P, out);
}

// Round 18
// 66.259 us; speedup vs baseline: 1.0323x; 1.0323x over previous
//
#include <hip/hip_runtime.h>

#define BB 8192
#define TT 50
#define II 50
#define HH 10
#define CC 5

__device__ __forceinline__ float fast_tanh(float x) {
    float e = __expf(2.0f * x);
    return 1.0f - 2.0f * __builtin_amdgcn_rcpf(e + 1.0f);
}

// {u,v} <- {self, xor-16 partner} (order HW-defined; used for commutative sums
// only -> orientation-immune). Verified working rounds 4-8, 14, 15.
__device__ __forceinline__ float xsum16(float a) {
#if __has_builtin(__builtin_amdgcn_permlane16_swap)
    auto r = __builtin_amdgcn_permlane16_swap(__float_as_uint(a), __float_as_uint(a), false, false);
    return __uint_as_float(r[0]) + __uint_as_float(r[1]);
#else
    float u = a, v = a;
    asm("s_nop 1\n\tv_permlane16_swap_b32 %0, %1\n\ts_nop 0" : "+v"(u), "+v"(v));
    return u + v;
#endif
}

// K1: P[t][j][b] = sum_i x[b][t][i] * Wih0[j][i] + (bih0[j]+bhh0[j])
// R10's exact version — coalesced dword stores per j-row (~15.5 us timed).
__global__ __launch_bounds__(256) void k_proj0(
    const float* __restrict__ x, const float* __restrict__ Wih0,
    const float* __restrict__ bih0, const float* __restrict__ bhh0,
    float* __restrict__ P) {
    int gid = blockIdx.x * 256 + threadIdx.x;
    int b = gid & (BB - 1);
    int t = gid >> 13;
    const float2* xr = (const float2*)(x + ((size_t)b * TT + t) * II);
    float2 xv[II / 2];
#pragma unroll
    for (int i = 0; i < II / 2; i++) xv[i] = xr[i];
#pragma unroll
    for (int j = 0; j < HH; j++) {
        float a = bih0[j] + bhh0[j];
        const float2* w = (const float2*)(Wih0 + j * II);
#pragma unroll
        for (int i = 0; i < II / 2; i++) {
            float2 wv = w[i];
            a = fmaf(wv.x, xv[i].x, a);
            a = fmaf(wv.y, xv[i].y, a);
        }
        P[((size_t)t * HH + j) * BB + b] = a;
    }
}

// K2: fused 3-layer recurrence + FC (R14's kernel verbatim; only the three
// P-read address computations changed to the [t][j][b] layout).
// 32 lanes/batch: j = tid&15 (row), q = (tid>>4)&1 (k-half), bat = tid>>5.
// 2 batches/wave -> 4096 waves = 16 waves/CU. permlane16_swap cross-q reduce.
__global__ __launch_bounds__(256, 4) void k_fused(
    const float* __restrict__ h0all,
    const float* __restrict__ Whh0,
    const float* __restrict__ Wih1, const float* __restrict__ Whh1,
    const float* __restrict__ bih1, const float* __restrict__ bhh1,
    const float* __restrict__ Wih2, const float* __restrict__ Whh2,
    const float* __restrict__ bih2, const float* __restrict__ bhh2,
    const float* __restrict__ fcw, const float* __restrict__ fcb,
    const float* __restrict__ P, float* __restrict__ out) {
    __shared__ __align__(16) float sfc4[(TT * HH + 16) * 4];  // fcw c0-3, 16B rows (padded)
    __shared__ float sfc1[TT * HH + 16];                      // fcw c4 (padded)
    __shared__ __align__(16) float sh[2][8][2][5][4];         // [par][bat][q][k][{h0,h1,h2,pad}]

    const int tid = threadIdx.x;
    const int j = tid & 15;
    const int q = (tid >> 4) & 1;
    const int bat = tid >> 5;
    const int b = blockIdx.x * 8 + bat;
    const bool jv = (j < HH);
    const bool q0 = (q == 0);
    const bool writer = jv && ((j >= 5 ? 1 : 0) == q);
    const int kk0 = j - 5 * q;   // writer's k slot (valid when writer)

    // ---- stage FC weights (padded zero tail) ----
    for (int r = tid; r < TT * HH + 16; r += 256) {
        bool v = r < TT * HH;
#pragma unroll
        for (int c = 0; c < 4; c++)
            sfc4[r * 4 + c] = v ? fcw[(size_t)c * (TT * HH) + r] : 0.0f;
        sfc1[r] = v ? fcw[(size_t)4 * (TT * HH) + r] : 0.0f;
    }

    // ---- per-lane weight quarters: row j, k in [5q, 5q+5) ----
    float w0r[5], wi1r[5], wh1r[5], wi2r[5], wh2r[5];
#pragma unroll
    for (int kk = 0; kk < 5; kk++) {
        int k = 5 * q + kk;
        w0r[kk]  = jv ? Whh0[j * HH + k] : 0.0f;
        wi1r[kk] = jv ? Wih1[j * HH + k] : 0.0f;
        wh1r[kk] = jv ? Whh1[j * HH + k] : 0.0f;
        wi2r[kk] = jv ? Wih2[j * HH + k] : 0.0f;
        wh2r[kk] = jv ? Whh2[j * HH + k] : 0.0f;
    }
    const float bs1 = (jv && q0) ? (bih1[j] + bhh1[j]) : 0.0f;
    const float bs2 = (jv && q0) ? (bih2[j] + bhh2[j]) : 0.0f;

    float h0i = 0.0f, h1i = 0.0f, h2i = 0.0f;
    if (jv) {
        h0i = h0all[(size_t)b * HH + j];
        h1i = h0all[(size_t)BB * HH + (size_t)b * HH + j];
        h2i = h0all[(size_t)2 * BB * HH + (size_t)b * HH + j];
    }
    // prologue: initial state into read-parity of iteration 0 (pr = 1)
    if (writer) {
        float4 wv; wv.x = h0i; wv.y = h1i; wv.z = h2i; wv.w = 0.0f;
        *(float4*)&sh[1][bat][q][kk0][0] = wv;
    }

    __syncthreads();   // sfc ready; waves independent afterwards

    float acc[CC] = {0.0f, 0.0f, 0.0f, 0.0f, 0.0f};
    // 2-deep P rotation: pc = P[t=i], p1 = P[t=i+1]   ([t][j][b] layout)
    float pc = (q0 && jv) ? P[((size_t)0 * HH + j) * BB + b] : 0.0f;
    float p1 = (q0 && jv) ? P[((size_t)1 * HH + j) * BB + b] : 0.0f;

#pragma unroll 1
    for (int i = 0; i < TT + 2; i++) {
        const int pr = (i + 1) & 1;
        const int pw = i & 1;

        // ---- h reads: 5 x b128, {h0,h1,h2}[5q+kk] ----
        float4 hk0 = *(const float4*)&sh[pr][bat][q][0][0];
        float4 hk1 = *(const float4*)&sh[pr][bat][q][1][0];
        float4 hk2 = *(const float4*)&sh[pr][bat][q][2][0];
        float4 hk3 = *(const float4*)&sh[pr][bat][q][3][0];
        float4 hk4 = *(const float4*)&sh[pr][bat][q][4][0];

        // ---- prefetch P for t = i+2 ([t][j][b] layout) ----
        int tp = (i + 2 < TT) ? (i + 2) : (TT - 1);
        float p2 = (q0 && jv) ? P[((size_t)tp * HH + j) * BB + b] : 0.0f;

        // ---- FC weights for t = i-2 (q0 lanes; padded-safe for j>=10) ----
        int tauc = (i >= 2) ? (i - 2) : 0;
        float4 f4 = {0.f, 0.f, 0.f, 0.f};
        float f1 = 0.0f;
        if (q0) {
            f4 = *(const float4*)&sfc4[(tauc * HH + j) * 4];
            f1 = sfc1[tauc * HH + j];
        }

        // ---- partial dots over own k-half ----
        float a0 = q0 ? pc : 0.0f;
        float a1 = bs1;
        float a2 = bs2;
        a0 = fmaf(w0r[0], hk0.x, a0); a1 = fmaf(wi1r[0], hk0.x, a1);
        a1 = fmaf(wh1r[0], hk0.y, a1); a2 = fmaf(wi2r[0], hk0.y, a2);
        a2 = fmaf(wh2r[0], hk0.z, a2);
        a0 = fmaf(w0r[1], hk1.x, a0); a1 = fmaf(wi1r[1], hk1.x, a1);
        a1 = fmaf(wh1r[1], hk1.y, a1); a2 = fmaf(wi2r[1], hk1.y, a2);
        a2 = fmaf(wh2r[1], hk1.z, a2);
        a0 = fmaf(w0r[2], hk2.x, a0); a1 = fmaf(wi1r[2], hk2.x, a1);
        a1 = fmaf(wh1r[2], hk2.y, a1); a2 = fmaf(wi2r[2], hk2.y, a2);
        a2 = fmaf(wh2r[2], hk2.z, a2);
        a0 = fmaf(w0r[3], hk3.x, a0); a1 = fmaf(wi1r[3], hk3.x, a1);
        a1 = fmaf(wh1r[3], hk3.y, a1); a2 = fmaf(wi2r[3], hk3.y, a2);
        a2 = fmaf(wh2r[3], hk3.z, a2);
        a0 = fmaf(w0r[4], hk4.x, a0); a1 = fmaf(wi1r[4], hk4.x, a1);
        a1 = fmaf(wh1r[4], hk4.y, a1); a2 = fmaf(wi2r[4], hk4.y, a2);
        a2 = fmaf(wh2r[4], hk4.z, a2);

        // ---- cross-q reduce (commutative, orientation-immune) + tanh ----
        float t0 = fast_tanh(xsum16(a0));
        float t1 = fast_tanh(xsum16(a1));
        float t2 = fast_tanh(xsum16(a2));

        // ---- FC accumulate for t = i-2 (t2 == 0 for j >= 10) ----
        if (i >= 2 && q0) {
            float rl = fmaxf(t2, 0.0f);
            acc[0] = fmaf(f4.x, rl, acc[0]);
            acc[1] = fmaf(f4.y, rl, acc[1]);
            acc[2] = fmaf(f4.z, rl, acc[2]);
            acc[3] = fmaf(f4.w, rl, acc[3]);
            acc[4] = fmaf(f1,  rl, acc[4]);
        }

        // ---- write next state (one b128; init overrides during fill) ----
        if (writer) {
            float4 wv;
            wv.x = t0;
            wv.y = (i == 0) ? h1i : t1;
            wv.z = (i <= 1) ? h2i : t2;
            wv.w = 0.0f;
            *(float4*)&sh[pw][bat][q][kk0][0] = wv;
        }
        pc = p1;
        p1 = p2;
    }

    // reduce acc across 16-lane j-group (q0 lanes; j>=10 hold zeros)
#pragma unroll
    for (int c = 0; c < CC; c++) {
        float a = acc[c];
        a += __shfl_xor(a, 1);
        a += __shfl_xor(a, 2);
        a += __shfl_xor(a, 4);
        a += __shfl_xor(a, 8);
        acc[c] = a + fcb[c];
    }
    if (q0 && j == 0) {
#pragma unroll
        for (int c = 0; c < CC; c++) out[(size_t)b * CC + c] = acc[c];
    }
}

extern "C" void kernel_launch(void* const* d_in, const int* in_sizes, int n_in,
                              void* d_out, int out_size, void* d_ws, size_t ws_size,
                              hipStream_t stream) {
    const float* x    = (const float*)d_in[0];
    const float* h0   = (const float*)d_in[1];
    const float* Wih0 = (const float*)d_in[2];
    const float* Whh0 = (const float*)d_in[3];
    const float* bih0 = (const float*)d_in[4];
    const float* bhh0 = (const float*)d_in[5];
    const float* Wih1 = (const float*)d_in[6];
    const float* Whh1 = (const float*)d_in[7];
    const float* bih1 = (const float*)d_in[8];
    const float* bhh1 = (const float*)d_in[9];
    const float* Wih2 = (const float*)d_in[10];
    const float* Whh2 = (const float*)d_in[11];
    const float* bih2 = (const float*)d_in[12];
    const float* bhh2 = (const float*)d_in[13];
    const float* fcw  = (const float*)d_in[14];
    const float* fcb  = (const float*)d_in[15];
    float* out = (float*)d_out;
    float* P   = (float*)d_ws;   // [T][H][B] = 16.38 MB

    k_proj0<<<(BB * TT) / 256, 256, 0, stream>>>(x, Wih0, bih0, bhh0, P);
    k_fused<<<BB / 8, 256, 0, stream>>>(h0, Whh0, Wih1, Whh1, bih1, bhh1,
                                        Wih2, Whh2, bih2, bhh2, fcw, fcb, P, out);
}